// Round 8
// baseline (699.217 us; speedup 1.0000x reference)
//
#include <hip/hip_runtime.h>
#include <hip/hip_bf16.h>
#include <cstdint>
#include <cstddef>

#define N_NODES 20000
#define N_EDGES 40000
#define EPAD 40192             // 157*256, padded edge count
#define N_GRAPHS 800
#define ATOM 64
#define MLP1D 512
#define MLP2D 256
#define NOUT 34

typedef _Float16 h2 __attribute__((ext_vector_type(2)));
typedef _Float16 half8 __attribute__((ext_vector_type(8)));
typedef float f32x4 __attribute__((ext_vector_type(4)));

__device__ __forceinline__ float sigm(float x) { return 1.f / (1.f + expf(-x)); }

// ---------------- fused prep: lin + heprep + Bf-build + misc ----------------
#define LIN_BLKS 5000
#define HEP_BLKS (EPAD / 64)                  // 628
#define BF_TOTAL (129 * 4096)                 // 528384
#define BF_BLKS ((BF_TOTAL + 255) / 256)      // 2064
#define MISC_TOTAL (12288 + 12288 + 32768 + 16384 + EPAD + (N_GRAPHS + 1) + N_EDGES)
#define MISC_BLKS ((MISC_TOTAL + 255) / 256)
#define PREP_BLKS (LIN_BLKS + HEP_BLKS + BF_BLKS + MISC_BLKS)

__global__ __launch_bounds__(256) void prep_all(
    const float* __restrict__ x_feat, const float* __restrict__ W_lin,
    const float* __restrict__ b_lin, float* __restrict__ hx, _Float16* __restrict__ xh,
    const float* __restrict__ ea, const float* __restrict__ W_e1,
    const float* __restrict__ b_e1, _Float16* __restrict__ heT,
    const float* __restrict__ We2, const float* __restrict__ be2, _Float16* __restrict__ Bf,
    const float* __restrict__ gWih, const float* __restrict__ gWhh,
    const float* __restrict__ lWih, const float* __restrict__ lWhh,
    _Float16* __restrict__ gWihT, _Float16* __restrict__ gWhhT,
    _Float16* __restrict__ lWihT, _Float16* __restrict__ lWhhT,
    const int* __restrict__ batch, int* __restrict__ gstart,
    const int* __restrict__ dst, float* __restrict__ deg) {
    int bx = blockIdx.x;
    if (bx < LIN_BLKS) {
        __shared__ float xr[4][64];
        int ln = threadIdx.x >> 6, j = threadIdx.x & 63;
        int n = (bx << 2) + ln;
        xr[ln][j] = x_feat[(size_t)n * 64 + j];
        __syncthreads();
        float acc = b_lin[j];
        for (int i = 0; i < 64; ++i) acc = fmaf(xr[ln][i], W_lin[i * 64 + j], acc);
        float r = fmaxf(acc, 0.f);
        hx[(size_t)n * 64 + j] = r;
        xh[(size_t)n * 64 + j] = (_Float16)r;
        return;
    }
    bx -= LIN_BLKS;
    if (bx < HEP_BLKS) {
        __shared__ float eaL[64 * 17];
        int e0 = bx * 64;
        for (int idx = threadIdx.x; idx < 1024; idx += 256) {
            int r = idx >> 4, i = idx & 15;
            int e = e0 + r;
            eaL[r * 17 + i] = (e < N_EDGES) ? ea[(size_t)e * 16 + i] : 0.f;
        }
        __syncthreads();
        int w = threadIdx.x >> 6, lane = threadIdx.x & 63;
        for (int c = w; c < 128; c += 4) {
            float acc = b_e1[c];
            #pragma unroll
            for (int i = 0; i < 16; ++i)
                acc = fmaf(eaL[lane * 17 + i], W_e1[i * 128 + c], acc);
            heT[(size_t)c * EPAD + e0 + lane] = (_Float16)fmaxf(acc, 0.f);
        }
        return;
    }
    bx -= HEP_BLKS;
    if (bx < BF_BLKS) {
        int idx = bx * 256 + threadIdx.x;
        if (idx >= BF_TOTAL) return;
        int j = idx & 7, lane = (idx >> 3) & 63, ft = (idx >> 9) & 3;
        int kh = (idx >> 11) & 1, c = idx >> 12;
        int k = kh * 32 + (lane >> 4) * 8 + j;
        int f = ft * 16 + (lane & 15);
        float v = (c < 128) ? We2[(size_t)c * 4096 + k * 64 + f] : be2[k * 64 + f];
        Bf[idx] = (_Float16)v;
        return;
    }
    bx -= BF_BLKS;
    {
        int i = bx * 256 + threadIdx.x;
        if (i < 12288) { int r = i / 64, c = i % 64; gWihT[c * 192 + r] = (_Float16)gWih[i]; return; }
        i -= 12288;
        if (i < 12288) { int r = i / 64, c = i % 64; gWhhT[c * 192 + r] = (_Float16)gWhh[i]; return; }
        i -= 12288;
        if (i < 32768) { int r = i / 128, c = i % 128; lWihT[c * 256 + r] = (_Float16)lWih[i]; return; }
        i -= 32768;
        if (i < 16384) { int r = i / 64, c = i % 64; lWhhT[c * 256 + r] = (_Float16)lWhh[i]; return; }
        i -= 16384;
        if (i < EPAD) { heT[(size_t)128 * EPAD + i] = (_Float16)1.0f; return; }
        i -= EPAD;
        if (i <= N_GRAPHS) {
            if (i == N_GRAPHS) { gstart[i] = N_NODES; return; }
            int lo = 0, hi = N_NODES;
            while (lo < hi) { int mid = (lo + hi) >> 1; if (batch[mid] < i) lo = mid + 1; else hi = mid; }
            gstart[i] = lo;
            return;
        }
        i -= (N_GRAPHS + 1);
        if (i < N_EDGES) { atomicAdd(&deg[dst[i]], 1.f); return; }
    }
}

// ---------------- message passing v7: f-split, full-K per wave, 1x atomics ----------------
// msg[e,f] = sum_c he[e,c] * (x[src_e] @ W_c)[f]; he folded into A-frag.
// Block = 64 edges x 4 waves (one 16-col f-slice per wave); full 129-c loop, rotated
// start, ping-pong register double-buffer. Each (e,f) produced ONCE -> 2.56M atomics
// total (vs 20.5M with K-split): removes the atomic-rate floor.
__global__ __launch_bounds__(256) void msg_v7(
    const _Float16* __restrict__ Bf, const _Float16* __restrict__ heT,
    const _Float16* __restrict__ xh, const int* __restrict__ src,
    const int* __restrict__ dst, float* __restrict__ agg)
{
    int tid = threadIdx.x;
    int ft = tid >> 6, lane = tid & 63;
    int lr = lane & 15, lk = lane >> 4;
    int m0 = blockIdx.x * 64;

    // persistent x[src] fragments (shared edges across the 4 waves -> L1 broadcast)
    h2 xf[4][2][4];
    #pragma unroll
    for (int et = 0; et < 4; ++et) {
        int e = m0 + et * 16 + lr;
        const _Float16* xp = xh + (size_t)src[e] * 64 + lk * 8;
        #pragma unroll
        for (int kh = 0; kh < 2; ++kh)
            #pragma unroll
            for (int j = 0; j < 4; ++j)
                xf[et][kh][j] = *(const h2*)(xp + kh * 32 + j * 2);
    }

    f32x4 acc[4] = {};
    const _Float16* bbase = Bf + ft * 512 + lane * 8;

    half8 bA[2], bB[2];
    _Float16 hA[4], hB[4];

    auto LOADB = [&](int c, half8* bb, _Float16* hh) {
        const _Float16* bp = bbase + (size_t)c * 4096;
        bb[0] = *(const half8*)(bp);
        bb[1] = *(const half8*)(bp + 2048);
        const _Float16* hp = heT + (size_t)c * EPAD + m0;
        hh[0] = hp[lr]; hh[1] = hp[16 + lr]; hh[2] = hp[32 + lr]; hh[3] = hp[48 + lr];
    };
    auto COMP = [&](const half8* bb, const _Float16* hh) {
        #pragma unroll
        for (int kh = 0; kh < 2; ++kh)
            #pragma unroll
            for (int et = 0; et < 4; ++et) {
                h2 hv = (h2){hh[et], hh[et]};
                union { h2 p[4]; half8 v; } a;
                #pragma unroll
                for (int j = 0; j < 4; ++j) a.p[j] = hv * xf[et][kh][j];
                acc[et] = __builtin_amdgcn_mfma_f32_16x16x32_f16(a.v, bb[kh], acc[et], 0, 0, 0);
            }
    };

    int c = blockIdx.x % 129;                  // rotated start, wraps mod 129
    LOADB(c, bA, hA);
    for (int t = 0; t < 64; ++t) {
        int c1 = (c + 1 == 129) ? 0 : c + 1;
        LOADB(c1, bB, hB);
        COMP(bA, hA);
        int c2 = (c1 + 1 == 129) ? 0 : c1 + 1;
        LOADB(c2, bA, hA);
        COMP(bB, hB);
        c = c2;
    }
    COMP(bA, hA);                              // 129th

    // scatter: f = ft*16+lr, edge row = et*16 + lk*4 + r2; one atomic per output
    #pragma unroll
    for (int et = 0; et < 4; ++et)
        #pragma unroll
        for (int r2 = 0; r2 < 4; ++r2) {
            int e = m0 + et * 16 + lk * 4 + r2;
            if (e < N_EDGES)
                atomicAdd(&agg[(size_t)dst[e] * 64 + ft * 16 + lr], acc[et][r2]);
        }
}

// agg -> mean -> +b_conv -> relu -> GRU; LDS-staged fp16 weights; re-zeroes agg.
__global__ __launch_bounds__(256) void gru_kernel(float* __restrict__ agg,
    const float* __restrict__ deg, const float* __restrict__ bconv,
    const _Float16* __restrict__ WihT, const _Float16* __restrict__ WhhT,  // [64][192] fp16
    const float* __restrict__ bih, const float* __restrict__ bhh,
    float* __restrict__ hx, _Float16* __restrict__ xh) {
    __shared__ _Float16 WI[64 * 192];
    __shared__ _Float16 WH[64 * 192];
    __shared__ float mh[4][2][64];
    int tid = threadIdx.x;
    int ln = tid >> 6, j = tid & 63;
    int n = (blockIdx.x << 2) + ln;
    float dg = fmaxf(deg[n], 1.f);
    size_t idx = (size_t)n * 64 + j;
    float m = fmaxf(agg[idx] / dg + bconv[j], 0.f);
    agg[idx] = 0.f;
    float h = hx[idx];
    mh[ln][0][j] = m; mh[ln][1][j] = h;
    {   // stage weights (6144 dwords each)
        const uint32_t* si = (const uint32_t*)WihT;
        const uint32_t* sh = (const uint32_t*)WhhT;
        uint32_t* di = (uint32_t*)WI;
        uint32_t* dh = (uint32_t*)WH;
        for (int i = tid; i < 6144; i += 256) { di[i] = si[i]; dh[i] = sh[i]; }
    }
    __syncthreads();
    float gri = bih[j], gzi = bih[64 + j], gni = bih[128 + j];
    float grh = bhh[j], gzh = bhh[64 + j], gnh = bhh[128 + j];
    for (int i = 0; i < 64; ++i) {
        float mi = mh[ln][0][i], hi = mh[ln][1][i];
        gri = fmaf(mi, (float)WI[i * 192 + j], gri);
        gzi = fmaf(mi, (float)WI[i * 192 + 64 + j], gzi);
        gni = fmaf(mi, (float)WI[i * 192 + 128 + j], gni);
        grh = fmaf(hi, (float)WH[i * 192 + j], grh);
        gzh = fmaf(hi, (float)WH[i * 192 + 64 + j], gzh);
        gnh = fmaf(hi, (float)WH[i * 192 + 128 + j], gnh);
    }
    float rr = sigm(gri + grh);
    float zz = sigm(gzi + gzh);
    float nn = tanhf(gni + rr * gnh);
    float hnew = (1.f - zz) * nn + zz * h;
    hx[idx] = hnew;
    xh[idx] = (_Float16)hnew;
}

// ---------------- fused Set2Set: LDS-staged fp16 LSTM weights, 1 wave/graph ----------------
// dynamic LDS: WI 128x256 fp16 (64KB) + WH 64x256 fp16 (32KB)
__global__ void s2s_kernel(const float* __restrict__ x, const int* __restrict__ gstart,
    const _Float16* __restrict__ lWihT,   // [128][256] fp16
    const _Float16* __restrict__ lWhhT,   // [64][256] fp16
    const float* __restrict__ bih, const float* __restrict__ bhh,
    float* __restrict__ qstar) {
    extern __shared__ _Float16 smem[];
    _Float16* WI = smem;            // 32768 halves
    _Float16* WH = smem + 32768;    // 16384 halves
    int g = blockIdx.x, j = threadIdx.x;
    {
        const uint32_t* si = (const uint32_t*)lWihT;
        const uint32_t* sh = (const uint32_t*)lWhhT;
        uint32_t* di = (uint32_t*)WI;
        uint32_t* dh = (uint32_t*)WH;
        for (int i = j; i < 16384; i += 64) di[i] = si[i];
        for (int i = j; i < 8192; i += 64) dh[i] = sh[i];
    }
    __syncthreads();
    int s0 = gstart[g], s1 = gstart[g + 1];
    float qv = 0.f, rv = 0.f, h = 0.f, c = 0.f;
    for (int s = 0; s < 3; ++s) {
        float g0 = bih[j] + bhh[j];
        float g1 = bih[64 + j] + bhh[64 + j];
        float g2 = bih[128 + j] + bhh[128 + j];
        float g3 = bih[192 + j] + bhh[192 + j];
        for (int i = 0; i < 64; ++i) {
            float qi = __shfl(qv, i);
            g0 = fmaf(qi, (float)WI[i * 256 + j], g0);
            g1 = fmaf(qi, (float)WI[i * 256 + 64 + j], g1);
            g2 = fmaf(qi, (float)WI[i * 256 + 128 + j], g2);
            g3 = fmaf(qi, (float)WI[i * 256 + 192 + j], g3);
        }
        for (int i = 0; i < 64; ++i) {
            float ri = __shfl(rv, i);
            g0 = fmaf(ri, (float)WI[(64 + i) * 256 + j], g0);
            g1 = fmaf(ri, (float)WI[(64 + i) * 256 + 64 + j], g1);
            g2 = fmaf(ri, (float)WI[(64 + i) * 256 + 128 + j], g2);
            g3 = fmaf(ri, (float)WI[(64 + i) * 256 + 192 + j], g3);
        }
        for (int i = 0; i < 64; ++i) {
            float hi2 = __shfl(h, i);
            g0 = fmaf(hi2, (float)WH[i * 256 + j], g0);
            g1 = fmaf(hi2, (float)WH[i * 256 + 64 + j], g1);
            g2 = fmaf(hi2, (float)WH[i * 256 + 128 + j], g2);
            g3 = fmaf(hi2, (float)WH[i * 256 + 192 + j], g3);
        }
        float ig = sigm(g0), fg = sigm(g1), cg = tanhf(g2), og = sigm(g3);
        c = fg * c + ig * cg;
        h = og * tanhf(c);
        qv = h;
        float emax = -3.0e38f;
        for (int n = s0; n < s1; ++n) {
            float v = x[(size_t)n * 64 + j] * qv;
            for (int o = 32; o; o >>= 1) v += __shfl_xor(v, o);
            emax = fmaxf(emax, v);
        }
        float esum = 0.f, racc = 0.f;
        for (int n = s0; n < s1; ++n) {
            float xv = x[(size_t)n * 64 + j];
            float v = xv * qv;
            for (int o = 32; o; o >>= 1) v += __shfl_xor(v, o);
            float ww = expf(v - emax);
            esum += ww;
            racc = fmaf(ww, xv, racc);
        }
        rv = racc / esum;
    }
    qstar[g * 128 + j] = qv;
    qstar[g * 128 + 64 + j] = rv;
}

// ---------------- head ----------------
__global__ void bn_kernel(const float* __restrict__ qs, const float* __restrict__ gamma,
                          const float* __restrict__ beta, float* __restrict__ out) {
    int c = blockIdx.x, l = threadIdx.x;
    float s = 0.f, ss = 0.f;
    for (int r = l; r < N_GRAPHS; r += 64) {
        float v = qs[r * 128 + c];
        s += v; ss += v * v;
    }
    for (int o = 32; o; o >>= 1) { s += __shfl_xor(s, o); ss += __shfl_xor(ss, o); }
    float mu = s * (1.f / N_GRAPHS);
    float var = ss * (1.f / N_GRAPHS) - mu * mu;
    float inv = rsqrtf(var + 1e-5f);
    float ga = gamma[c], be = beta[c];
    for (int r = l; r < N_GRAPHS; r += 64)
        out[r * 128 + c] = ga * (qs[r * 128 + c] - mu) * inv + be;
}

__global__ __launch_bounds__(512) void head_fused(const float* __restrict__ bno,
    const float* __restrict__ Wm1, const float* __restrict__ bm1,
    const float* __restrict__ Wm2, const float* __restrict__ bm2,
    const float* __restrict__ Wp, const float* __restrict__ bp,
    float* __restrict__ out) {
    __shared__ float row[128];
    __shared__ float y1[512];
    __shared__ float y2[256];
    int g = blockIdx.x, t = threadIdx.x;
    int rot = (g * 17) & 127;
    if (t < 128) row[t] = bno[g * 128 + t];
    __syncthreads();
    float acc = bm1[t];
    for (int s = 0; s < 128; ++s) {
        int i = (s + rot) & 127;
        acc = fmaf(row[i], Wm1[i * MLP1D + t], acc);
    }
    y1[t] = fmaxf(acc, 0.f);
    __syncthreads();
    if (t < 256) {
        float a2 = bm2[t];
        int rot2 = (g * 31) & 511;
        for (int s = 0; s < 512; ++s) {
            int i = (s + rot2) & 511;
            a2 = fmaf(y1[i], Wm2[i * MLP2D + t], a2);
        }
        y2[t] = fmaxf(a2, 0.f);
    }
    __syncthreads();
    if (t < NOUT) {
        float a3 = bp[t];
        int rot3 = (g * 13) & 255;
        for (int s = 0; s < 256; ++s) {
            int i = (s + rot3) & 255;
            a3 = fmaf(y2[i], Wp[i * NOUT + t], a3);
        }
        out[g * NOUT + t] = a3;
    }
}

// ---------------- launch ----------------
extern "C" void kernel_launch(void* const* d_in, const int* in_sizes, int n_in,
                              void* d_out, int out_size, void* d_ws, size_t ws_size,
                              hipStream_t stream) {
    (void)in_sizes; (void)n_in; (void)out_size; (void)ws_size;
    const float* x_feat    = (const float*)d_in[0];
    const float* edge_attr = (const float*)d_in[1];
    const int*   eidx      = (const int*)d_in[2];
    const int*   batch     = (const int*)d_in[3];
    const float* W_lin = (const float*)d_in[4];
    const float* b_lin = (const float*)d_in[5];
    const float* W_e1  = (const float*)d_in[6];
    const float* b_e1  = (const float*)d_in[7];
    const float* W_e2  = (const float*)d_in[8];
    const float* b_e2  = (const float*)d_in[9];
    const float* b_conv= (const float*)d_in[10];
    const float* gWih  = (const float*)d_in[11];
    const float* gWhh  = (const float*)d_in[12];
    const float* gbih  = (const float*)d_in[13];
    const float* gbhh  = (const float*)d_in[14];
    const float* lWih  = (const float*)d_in[15];
    const float* lWhh  = (const float*)d_in[16];
    const float* lbih  = (const float*)d_in[17];
    const float* lbhh  = (const float*)d_in[18];
    const float* bng   = (const float*)d_in[19];
    const float* bnb   = (const float*)d_in[20];
    const float* Wm1   = (const float*)d_in[21];
    const float* bm1   = (const float*)d_in[22];
    const float* Wm2   = (const float*)d_in[23];
    const float* bm2   = (const float*)d_in[24];
    const float* Wp    = (const float*)d_in[25];
    const float* bp    = (const float*)d_in[26];
    float* out = (float*)d_out;

    const int* src = eidx;
    const int* dst = eidx + N_EDGES;

    char* w = (char*)d_ws;
    size_t off = 0;
    auto alloc = [&](size_t bytes) -> char* {
        char* p = w + off; off += (bytes + 255) & ~(size_t)255; return p;
    };
    _Float16* Bf     = (_Float16*)alloc((size_t)129 * 4096 * 2);     // 1.06 MB
    _Float16* heT    = (_Float16*)alloc((size_t)129 * EPAD * 2);     // 10.4 MB
    _Float16* xh     = (_Float16*)alloc((size_t)N_NODES * 64 * 2);   // 2.56 MB
    float* hx        = (float*)alloc((size_t)N_NODES * 64 * 4);      // 5.12 MB
    float* agg       = (float*)alloc((size_t)N_NODES * 64 * 4);      // 5.12 MB
    float* deg       = (float*)alloc((size_t)N_NODES * 4);
    _Float16* gWihT  = (_Float16*)alloc(192 * 64 * 2);
    _Float16* gWhhT  = (_Float16*)alloc(192 * 64 * 2);
    _Float16* lWihT  = (_Float16*)alloc(256 * 128 * 2);
    _Float16* lWhhT  = (_Float16*)alloc(256 * 64 * 2);
    float* qstar     = (float*)alloc((size_t)N_GRAPHS * 128 * 4);
    int*   gst       = (int*)alloc((N_GRAPHS + 1) * 4);
    float* bno       = (float*)alloc((size_t)N_GRAPHS * 128 * 4);
    // total ~25 MB

    hipMemsetAsync(deg, 0, (size_t)N_NODES * 4, stream);
    hipMemsetAsync(agg, 0, (size_t)N_NODES * 64 * 4, stream);

    prep_all<<<PREP_BLKS, 256, 0, stream>>>(
        x_feat, W_lin, b_lin, hx, xh,
        edge_attr, W_e1, b_e1, heT,
        W_e2, b_e2, Bf,
        gWih, gWhh, lWih, lWhh, gWihT, gWhhT, lWihT, lWhhT,
        batch, gst, dst, deg);

    for (int r = 0; r < 3; ++r) {
        msg_v7<<<EPAD / 64, 256, 0, stream>>>(Bf, heT, xh, src, dst, agg);
        gru_kernel<<<N_NODES / 4, 256, 0, stream>>>(agg, deg, b_conv, gWihT, gWhhT, gbih, gbhh, hx, xh);
    }

    s2s_kernel<<<N_GRAPHS, 64, 98304, stream>>>(hx, gst, lWihT, lWhhT, lbih, lbhh, qstar);

    bn_kernel<<<128, 64, 0, stream>>>(qstar, bng, bnb, bno);
    head_fused<<<N_GRAPHS, 512, 0, stream>>>(bno, Wm1, bm1, Wm2, bm2, Wp, bp, out);
}

// Round 9
// 489.891 us; speedup vs baseline: 1.4273x; 1.4273x over previous
//
#include <hip/hip_runtime.h>
#include <hip/hip_bf16.h>
#include <cstdint>
#include <cstddef>

#define N_NODES 20000
#define N_EDGES 40000
#define EPAD 40192             // 157*256, padded edge count
#define N_GRAPHS 800
#define ATOM 64
#define MLP1D 512
#define MLP2D 256
#define NOUT 34

typedef _Float16 h2 __attribute__((ext_vector_type(2)));
typedef _Float16 half8 __attribute__((ext_vector_type(8)));
typedef float f32x4 __attribute__((ext_vector_type(4)));

__device__ __forceinline__ float sigm(float x) { return 1.f / (1.f + expf(-x)); }

// ---------------- fused prep: lin + heprep + Bf-build + misc ----------------
#define LIN_BLKS 5000
#define HEP_BLKS (EPAD / 64)                  // 628
#define BF_TOTAL (129 * 4096)                 // 528384
#define BF_BLKS ((BF_TOTAL + 255) / 256)      // 2064
#define MISC_TOTAL (12288 + 12288 + 32768 + 16384 + EPAD + (N_GRAPHS + 1) + N_EDGES)
#define MISC_BLKS ((MISC_TOTAL + 255) / 256)
#define PREP_BLKS (LIN_BLKS + HEP_BLKS + BF_BLKS + MISC_BLKS)

__global__ __launch_bounds__(256) void prep_all(
    const float* __restrict__ x_feat, const float* __restrict__ W_lin,
    const float* __restrict__ b_lin, float* __restrict__ hx, _Float16* __restrict__ xh,
    const float* __restrict__ ea, const float* __restrict__ W_e1,
    const float* __restrict__ b_e1, _Float16* __restrict__ heT,
    const float* __restrict__ We2, const float* __restrict__ be2, _Float16* __restrict__ Bf,
    const float* __restrict__ gWih, const float* __restrict__ gWhh,
    const float* __restrict__ lWih, const float* __restrict__ lWhh,
    float* __restrict__ gWihT, float* __restrict__ gWhhT,
    _Float16* __restrict__ lWihT, _Float16* __restrict__ lWhhT,
    const int* __restrict__ batch, int* __restrict__ gstart,
    const int* __restrict__ dst, float* __restrict__ deg) {
    int bx = blockIdx.x;
    if (bx < LIN_BLKS) {
        __shared__ float xr[4][64];
        int ln = threadIdx.x >> 6, j = threadIdx.x & 63;
        int n = (bx << 2) + ln;
        xr[ln][j] = x_feat[(size_t)n * 64 + j];
        __syncthreads();
        float acc = b_lin[j];
        for (int i = 0; i < 64; ++i) acc = fmaf(xr[ln][i], W_lin[i * 64 + j], acc);
        float r = fmaxf(acc, 0.f);
        hx[(size_t)n * 64 + j] = r;
        xh[(size_t)n * 64 + j] = (_Float16)r;
        return;
    }
    bx -= LIN_BLKS;
    if (bx < HEP_BLKS) {
        __shared__ float eaL[64 * 17];
        int e0 = bx * 64;
        for (int idx = threadIdx.x; idx < 1024; idx += 256) {
            int r = idx >> 4, i = idx & 15;
            int e = e0 + r;
            eaL[r * 17 + i] = (e < N_EDGES) ? ea[(size_t)e * 16 + i] : 0.f;
        }
        __syncthreads();
        int w = threadIdx.x >> 6, lane = threadIdx.x & 63;
        for (int c = w; c < 128; c += 4) {
            float acc = b_e1[c];
            #pragma unroll
            for (int i = 0; i < 16; ++i)
                acc = fmaf(eaL[lane * 17 + i], W_e1[i * 128 + c], acc);
            heT[(size_t)c * EPAD + e0 + lane] = (_Float16)fmaxf(acc, 0.f);
        }
        return;
    }
    bx -= HEP_BLKS;
    if (bx < BF_BLKS) {
        int idx = bx * 256 + threadIdx.x;
        if (idx >= BF_TOTAL) return;
        int j = idx & 7, lane = (idx >> 3) & 63, ft = (idx >> 9) & 3;
        int kh = (idx >> 11) & 1, c = idx >> 12;
        int k = kh * 32 + (lane >> 4) * 8 + j;
        int f = ft * 16 + (lane & 15);
        float v = (c < 128) ? We2[(size_t)c * 4096 + k * 64 + f] : be2[k * 64 + f];
        Bf[idx] = (_Float16)v;
        return;
    }
    bx -= BF_BLKS;
    {
        int i = bx * 256 + threadIdx.x;
        if (i < 12288) { int r = i / 64, c = i % 64; gWihT[c * 192 + r] = gWih[i]; return; }
        i -= 12288;
        if (i < 12288) { int r = i / 64, c = i % 64; gWhhT[c * 192 + r] = gWhh[i]; return; }
        i -= 12288;
        if (i < 32768) { int r = i / 128, c = i % 128; lWihT[c * 256 + r] = (_Float16)lWih[i]; return; }
        i -= 32768;
        if (i < 16384) { int r = i / 64, c = i % 64; lWhhT[c * 256 + r] = (_Float16)lWhh[i]; return; }
        i -= 16384;
        if (i < EPAD) { heT[(size_t)128 * EPAD + i] = (_Float16)1.0f; return; }
        i -= EPAD;
        if (i <= N_GRAPHS) {
            if (i == N_GRAPHS) { gstart[i] = N_NODES; return; }
            int lo = 0, hi = N_NODES;
            while (lo < hi) { int mid = (lo + hi) >> 1; if (batch[mid] < i) lo = mid + 1; else hi = mid; }
            gstart[i] = lo;
            return;
        }
        i -= (N_GRAPHS + 1);
        if (i < N_EDGES) { atomicAdd(&deg[dst[i]], 1.f); return; }
    }
}

// ---------------- message passing v7: f-split, full-K per wave, 1x atomics ----------------
__global__ __launch_bounds__(256) void msg_v7(
    const _Float16* __restrict__ Bf, const _Float16* __restrict__ heT,
    const _Float16* __restrict__ xh, const int* __restrict__ src,
    const int* __restrict__ dst, float* __restrict__ agg)
{
    int tid = threadIdx.x;
    int ft = tid >> 6, lane = tid & 63;
    int lr = lane & 15, lk = lane >> 4;
    int m0 = blockIdx.x * 64;

    h2 xf[4][2][4];
    #pragma unroll
    for (int et = 0; et < 4; ++et) {
        int e = m0 + et * 16 + lr;
        const _Float16* xp = xh + (size_t)src[e] * 64 + lk * 8;
        #pragma unroll
        for (int kh = 0; kh < 2; ++kh)
            #pragma unroll
            for (int j = 0; j < 4; ++j)
                xf[et][kh][j] = *(const h2*)(xp + kh * 32 + j * 2);
    }

    f32x4 acc[4] = {};
    const _Float16* bbase = Bf + ft * 512 + lane * 8;

    half8 bA[2], bB[2];
    _Float16 hA[4], hB[4];

    auto LOADB = [&](int c, half8* bb, _Float16* hh) {
        const _Float16* bp = bbase + (size_t)c * 4096;
        bb[0] = *(const half8*)(bp);
        bb[1] = *(const half8*)(bp + 2048);
        const _Float16* hp = heT + (size_t)c * EPAD + m0;
        hh[0] = hp[lr]; hh[1] = hp[16 + lr]; hh[2] = hp[32 + lr]; hh[3] = hp[48 + lr];
    };
    auto COMP = [&](const half8* bb, const _Float16* hh) {
        #pragma unroll
        for (int kh = 0; kh < 2; ++kh)
            #pragma unroll
            for (int et = 0; et < 4; ++et) {
                h2 hv = (h2){hh[et], hh[et]};
                union { h2 p[4]; half8 v; } a;
                #pragma unroll
                for (int j = 0; j < 4; ++j) a.p[j] = hv * xf[et][kh][j];
                acc[et] = __builtin_amdgcn_mfma_f32_16x16x32_f16(a.v, bb[kh], acc[et], 0, 0, 0);
            }
    };

    int c = blockIdx.x % 129;
    LOADB(c, bA, hA);
    for (int t = 0; t < 64; ++t) {
        int c1 = (c + 1 == 129) ? 0 : c + 1;
        LOADB(c1, bB, hB);
        COMP(bA, hA);
        int c2 = (c1 + 1 == 129) ? 0 : c1 + 1;
        LOADB(c2, bA, hA);
        COMP(bB, hB);
        c = c2;
    }
    COMP(bA, hA);

    #pragma unroll
    for (int et = 0; et < 4; ++et)
        #pragma unroll
        for (int r2 = 0; r2 < 4; ++r2) {
            int e = m0 + et * 16 + lk * 4 + r2;
            if (e < N_EDGES)
                atomicAdd(&agg[(size_t)dst[e] * 64 + ft * 16 + lr], acc[et][r2]);
        }
}

// agg -> mean -> +b_conv -> relu -> GRU (round-5 form: global f32 weights); re-zeroes agg.
__global__ __launch_bounds__(256) void gru_kernel(float* __restrict__ agg,
    const float* __restrict__ deg, const float* __restrict__ bconv,
    const float* __restrict__ WihT, const float* __restrict__ WhhT,   // [64][192] f32
    const float* __restrict__ bih, const float* __restrict__ bhh,
    float* __restrict__ hx, _Float16* __restrict__ xh) {
    __shared__ float mh[4][2][64];
    int ln = threadIdx.x >> 6, j = threadIdx.x & 63;
    int n = (blockIdx.x << 2) + ln;
    float dg = fmaxf(deg[n], 1.f);
    size_t idx = (size_t)n * 64 + j;
    float m = fmaxf(agg[idx] / dg + bconv[j], 0.f);
    agg[idx] = 0.f;
    float h = hx[idx];
    mh[ln][0][j] = m; mh[ln][1][j] = h;
    __syncthreads();
    float gri = bih[j], gzi = bih[64 + j], gni = bih[128 + j];
    float grh = bhh[j], gzh = bhh[64 + j], gnh = bhh[128 + j];
    for (int i = 0; i < 64; ++i) {
        float mi = mh[ln][0][i], hi = mh[ln][1][i];
        gri = fmaf(mi, WihT[i * 192 + j], gri);
        gzi = fmaf(mi, WihT[i * 192 + 64 + j], gzi);
        gni = fmaf(mi, WihT[i * 192 + 128 + j], gni);
        grh = fmaf(hi, WhhT[i * 192 + j], grh);
        gzh = fmaf(hi, WhhT[i * 192 + 64 + j], gzh);
        gnh = fmaf(hi, WhhT[i * 192 + 128 + j], gnh);
    }
    float rr = sigm(gri + grh);
    float zz = sigm(gzi + gzh);
    float nn = tanhf(gni + rr * gnh);
    float hnew = (1.f - zz) * nn + zz * h;
    hx[idx] = hnew;
    xh[idx] = (_Float16)hnew;
}

// ---------------- Set2Set v2: 256 threads/graph, gate-per-thread, global fp16 weights ----
// thread t computes gate column t of gates[256] = [q,r]@WI + h@WH; state in LDS;
// attention split across the 4 waves with LDS combine. Weight loads on vmcnt -> pipelined.
__global__ __launch_bounds__(256) void s2s_kernel(const float* __restrict__ x,
    const int* __restrict__ gstart,
    const _Float16* __restrict__ WI,   // [128][256] fp16
    const _Float16* __restrict__ WH,   // [64][256] fp16
    const float* __restrict__ bih, const float* __restrict__ bhh,
    float* __restrict__ qstar) {
    __shared__ float st[192];          // q(0..63), r(64..127), h(128..191)
    __shared__ float gl[256];
    __shared__ float redmax[4], redsum[4];
    __shared__ float raccs[4][64];
    int g = blockIdx.x, t = threadIdx.x;
    int w = t >> 6, j = t & 63;
    int s0 = gstart[g], s1 = gstart[g + 1];
    if (t < 192) st[t] = 0.f;
    float cj = 0.f;
    float bsum = bih[t] + bhh[t];
    __syncthreads();
    for (int s = 0; s < 3; ++s) {
        float a0 = bsum, a1 = 0.f;
        #pragma unroll 8
        for (int i = 0; i < 128; i += 2) {
            a0 = fmaf(st[i], (float)WI[i * 256 + t], a0);
            a1 = fmaf(st[i + 1], (float)WI[(i + 1) * 256 + t], a1);
        }
        #pragma unroll 8
        for (int i = 0; i < 64; i += 2) {
            a0 = fmaf(st[128 + i], (float)WH[i * 256 + t], a0);
            a1 = fmaf(st[128 + i + 1], (float)WH[(i + 1) * 256 + t], a1);
        }
        gl[t] = a0 + a1;
        __syncthreads();
        if (t < 64) {
            float ig = sigm(gl[t]);
            float fg = sigm(gl[64 + t]);
            float cg = tanhf(gl[128 + t]);
            float og = sigm(gl[192 + t]);
            cj = fg * cj + ig * cg;
            float hnew = og * tanhf(cj);
            st[t] = hnew;        // q = h
            st[128 + t] = hnew;  // h
        }
        __syncthreads();
        float hj = st[128 + j];
        float pmax = -3.0e38f;
        for (int n = s0 + w; n < s1; n += 4) {
            float v = x[(size_t)n * 64 + j] * hj;
            for (int o = 32; o; o >>= 1) v += __shfl_xor(v, o);
            pmax = fmaxf(pmax, v);
        }
        if (j == 0) redmax[w] = pmax;
        __syncthreads();
        float emax = fmaxf(fmaxf(redmax[0], redmax[1]), fmaxf(redmax[2], redmax[3]));
        float esum = 0.f, racc = 0.f;
        for (int n = s0 + w; n < s1; n += 4) {
            float xv = x[(size_t)n * 64 + j];
            float v = xv * hj;
            for (int o = 32; o; o >>= 1) v += __shfl_xor(v, o);
            float ww = expf(v - emax);
            esum += ww;
            racc = fmaf(ww, xv, racc);
        }
        raccs[w][j] = racc;
        if (j == 0) redsum[w] = esum;
        __syncthreads();
        if (t < 64) {
            float es = redsum[0] + redsum[1] + redsum[2] + redsum[3];
            st[64 + j] = (raccs[0][j] + raccs[1][j] + raccs[2][j] + raccs[3][j]) / es;
        }
        __syncthreads();
    }
    if (t < 64) {
        qstar[g * 128 + t] = st[t];
        qstar[g * 128 + 64 + t] = st[64 + t];
    }
}

// ---------------- head ----------------
__global__ void bn_kernel(const float* __restrict__ qs, const float* __restrict__ gamma,
                          const float* __restrict__ beta, float* __restrict__ out) {
    int c = blockIdx.x, l = threadIdx.x;
    float s = 0.f, ss = 0.f;
    for (int r = l; r < N_GRAPHS; r += 64) {
        float v = qs[r * 128 + c];
        s += v; ss += v * v;
    }
    for (int o = 32; o; o >>= 1) { s += __shfl_xor(s, o); ss += __shfl_xor(ss, o); }
    float mu = s * (1.f / N_GRAPHS);
    float var = ss * (1.f / N_GRAPHS) - mu * mu;
    float inv = rsqrtf(var + 1e-5f);
    float ga = gamma[c], be = beta[c];
    for (int r = l; r < N_GRAPHS; r += 64)
        out[r * 128 + c] = ga * (qs[r * 128 + c] - mu) * inv + be;
}

__global__ __launch_bounds__(512) void head_fused(const float* __restrict__ bno,
    const float* __restrict__ Wm1, const float* __restrict__ bm1,
    const float* __restrict__ Wm2, const float* __restrict__ bm2,
    const float* __restrict__ Wp, const float* __restrict__ bp,
    float* __restrict__ out) {
    __shared__ float row[128];
    __shared__ float y1[512];
    __shared__ float y2[256];
    int g = blockIdx.x, t = threadIdx.x;
    int rot = (g * 17) & 127;
    if (t < 128) row[t] = bno[g * 128 + t];
    __syncthreads();
    float acc = bm1[t];
    for (int s = 0; s < 128; ++s) {
        int i = (s + rot) & 127;
        acc = fmaf(row[i], Wm1[i * MLP1D + t], acc);
    }
    y1[t] = fmaxf(acc, 0.f);
    __syncthreads();
    if (t < 256) {
        float a2 = bm2[t];
        int rot2 = (g * 31) & 511;
        for (int s = 0; s < 512; ++s) {
            int i = (s + rot2) & 511;
            a2 = fmaf(y1[i], Wm2[i * MLP2D + t], a2);
        }
        y2[t] = fmaxf(a2, 0.f);
    }
    __syncthreads();
    if (t < NOUT) {
        float a3 = bp[t];
        int rot3 = (g * 13) & 255;
        for (int s = 0; s < 256; ++s) {
            int i = (s + rot3) & 255;
            a3 = fmaf(y2[i], Wp[i * NOUT + t], a3);
        }
        out[g * NOUT + t] = a3;
    }
}

// ---------------- launch ----------------
extern "C" void kernel_launch(void* const* d_in, const int* in_sizes, int n_in,
                              void* d_out, int out_size, void* d_ws, size_t ws_size,
                              hipStream_t stream) {
    (void)in_sizes; (void)n_in; (void)out_size; (void)ws_size;
    const float* x_feat    = (const float*)d_in[0];
    const float* edge_attr = (const float*)d_in[1];
    const int*   eidx      = (const int*)d_in[2];
    const int*   batch     = (const int*)d_in[3];
    const float* W_lin = (const float*)d_in[4];
    const float* b_lin = (const float*)d_in[5];
    const float* W_e1  = (const float*)d_in[6];
    const float* b_e1  = (const float*)d_in[7];
    const float* W_e2  = (const float*)d_in[8];
    const float* b_e2  = (const float*)d_in[9];
    const float* b_conv= (const float*)d_in[10];
    const float* gWih  = (const float*)d_in[11];
    const float* gWhh  = (const float*)d_in[12];
    const float* gbih  = (const float*)d_in[13];
    const float* gbhh  = (const float*)d_in[14];
    const float* lWih  = (const float*)d_in[15];
    const float* lWhh  = (const float*)d_in[16];
    const float* lbih  = (const float*)d_in[17];
    const float* lbhh  = (const float*)d_in[18];
    const float* bng   = (const float*)d_in[19];
    const float* bnb   = (const float*)d_in[20];
    const float* Wm1   = (const float*)d_in[21];
    const float* bm1   = (const float*)d_in[22];
    const float* Wm2   = (const float*)d_in[23];
    const float* bm2   = (const float*)d_in[24];
    const float* Wp    = (const float*)d_in[25];
    const float* bp    = (const float*)d_in[26];
    float* out = (float*)d_out;

    const int* src = eidx;
    const int* dst = eidx + N_EDGES;

    char* w = (char*)d_ws;
    size_t off = 0;
    auto alloc = [&](size_t bytes) -> char* {
        char* p = w + off; off += (bytes + 255) & ~(size_t)255; return p;
    };
    _Float16* Bf     = (_Float16*)alloc((size_t)129 * 4096 * 2);     // 1.06 MB
    _Float16* heT    = (_Float16*)alloc((size_t)129 * EPAD * 2);     // 10.4 MB
    _Float16* xh     = (_Float16*)alloc((size_t)N_NODES * 64 * 2);   // 2.56 MB
    float* hx        = (float*)alloc((size_t)N_NODES * 64 * 4);      // 5.12 MB
    float* agg       = (float*)alloc((size_t)N_NODES * 64 * 4);      // 5.12 MB
    float* deg       = (float*)alloc((size_t)N_NODES * 4);
    float* gWihT     = (float*)alloc(192 * 64 * 4);
    float* gWhhT     = (float*)alloc(192 * 64 * 4);
    _Float16* lWihT  = (_Float16*)alloc(256 * 128 * 2);
    _Float16* lWhhT  = (_Float16*)alloc(256 * 64 * 2);
    float* qstar     = (float*)alloc((size_t)N_GRAPHS * 128 * 4);
    int*   gst       = (int*)alloc((N_GRAPHS + 1) * 4);
    float* bno       = (float*)alloc((size_t)N_GRAPHS * 128 * 4);
    // total ~25 MB

    hipMemsetAsync(deg, 0, (size_t)N_NODES * 4, stream);
    hipMemsetAsync(agg, 0, (size_t)N_NODES * 64 * 4, stream);

    prep_all<<<PREP_BLKS, 256, 0, stream>>>(
        x_feat, W_lin, b_lin, hx, xh,
        edge_attr, W_e1, b_e1, heT,
        W_e2, b_e2, Bf,
        gWih, gWhh, lWih, lWhh, gWihT, gWhhT, lWihT, lWhhT,
        batch, gst, dst, deg);

    for (int r = 0; r < 3; ++r) {
        msg_v7<<<EPAD / 64, 256, 0, stream>>>(Bf, heT, xh, src, dst, agg);
        gru_kernel<<<N_NODES / 4, 256, 0, stream>>>(agg, deg, b_conv, gWihT, gWhhT, gbih, gbhh, hx, xh);
    }

    s2s_kernel<<<N_GRAPHS, 256, 0, stream>>>(hx, gst, lWihT, lWhhT, lbih, lbhh, qstar);

    bn_kernel<<<128, 64, 0, stream>>>(qstar, bng, bnb, bno);
    head_fused<<<N_GRAPHS, 512, 0, stream>>>(bno, Wm1, bm1, Wm2, bm2, Wp, bp, out);
}